// Round 2
// baseline (490.134 us; speedup 1.0000x reference)
//
#include <hip/hip_runtime.h>
#include <hip/hip_bf16.h>
#include <stdint.h>
#include <stddef.h>

#define DI __device__ __forceinline__

typedef unsigned short u16;
typedef float f32x4 __attribute__((ext_vector_type(4)));
typedef short bf16x8 __attribute__((ext_vector_type(8)));
typedef u16 u16x4 __attribute__((ext_vector_type(4)));

constexpr int Mm = 8192;
constexpr int Dd = 1024;
constexpr float LOG2E = 1.44269504088896f;

DI u16 bf(float f) {
  __hip_bfloat16 h = __float2bfloat16(f);
  return *reinterpret_cast<u16*>(&h);
}

DI float b2f(short s) {
  union { float f; unsigned u; } v;
  v.u = ((unsigned)(unsigned short)s) << 16;
  return v.f;
}

DI f32x4 mfma16(bf16x8 a, bf16x8 b, f32x4 c) {
  return __builtin_amdgcn_mfma_f32_16x16x32_bf16(a, b, c, 0, 0, 0);
}

DI void gload16(const u16* g, u16* l) {
  __builtin_amdgcn_global_load_lds(
      (const __attribute__((address_space(1))) void*)(g),
      (__attribute__((address_space(3))) void*)(l), 16, 0, 0);
}

// ---------------- convert x (f32 -> bf16), 4 elems/thread ----------------
__global__ __launch_bounds__(256) void k_cvt(const float* __restrict__ x,
                                             u16* __restrict__ o) {
  size_t i = (size_t)blockIdx.x * 256 + threadIdx.x;
  float4 v = *(const float4*)(x + i * 4);
  u16x4 r;
  r.x = bf(v.x); r.y = bf(v.y); r.z = bf(v.z); r.w = bf(v.w);
  *(u16x4*)(o + i * 4) = r;
}

// ---------------- transpose 1024x1024 f32 W -> bf16 WT[n][k] ----------------
__global__ __launch_bounds__(256) void k_tr(const float* __restrict__ W,
                                            u16* __restrict__ WT) {
  __shared__ float t[32][33];
  int bx = blockIdx.x * 32;  // k block
  int by = blockIdx.y * 32;  // n block
  int tx = threadIdx.x, ty = threadIdx.y;  // (32,8)
#pragma unroll
  for (int i = 0; i < 4; ++i)
    t[ty + i * 8][tx] = W[(size_t)(bx + ty + i * 8) * 1024 + by + tx];
  __syncthreads();
#pragma unroll
  for (int i = 0; i < 4; ++i)
    WT[(size_t)(by + ty + i * 8) * 1024 + bx + tx] = bf(t[tx][ty + i * 8]);
}

// ---------------- GEMM (m97 structure): C[M,1024] = A @ WT^T ----------------
// MODE 0: Q  -> bf16 (acc+bias)*0.125*log2e, [m][d]
// MODE 1: K  -> bf16 acc+bias,               [m][d]
// MODE 2: V  -> bf16 acc+bias, transposed    [b][d][seq]
// MODE 3: O  -> f32 acc+bias+resid,          [m][d]
template <int MODE>
__global__ __launch_bounds__(256) void k_gemm(const u16* __restrict__ A,
                                              const u16* __restrict__ WT,
                                              const float* __restrict__ bias,
                                              const float* __restrict__ resid,
                                              void* __restrict__ outp) {
  __shared__ __align__(16) u16 As[128 * 64];  // linear [row][k], 128B rows
  __shared__ __align__(16) u16 Bs[128 * 64];
  const int tid = threadIdx.x;
  const int lane = tid & 63;
  const int wave = tid >> 6;
  const int brow = blockIdx.y * 128;
  const int bcol = blockIdx.x * 128;
  const int wr = (wave >> 1) * 64;
  const int wc = (wave & 1) * 64;
  const int l15 = lane & 15, l4 = lane >> 4;

  f32x4 acc[4][4] = {};
  const int crow0 = tid >> 3;        // chunk row for r=0
  const int kpos = (tid & 7) * 8;    // k offset within row

  for (int t = 0; t < 16; ++t) {
    const int k0 = t * 64;
#pragma unroll
    for (int r = 0; r < 4; ++r) {
      int crow = r * 32 + crow0;
      u16* ldsbase_a = (u16*)As + ((r * 256 + wave * 64) << 3);  // wave-uniform
      u16* ldsbase_b = (u16*)Bs + ((r * 256 + wave * 64) << 3);
      gload16(A + (size_t)(brow + crow) * 1024 + k0 + kpos, ldsbase_a);
      gload16(WT + (size_t)(bcol + crow) * 1024 + k0 + kpos, ldsbase_b);
    }
    __syncthreads();  // vmcnt(0) drain + barrier: LDS tile ready
#pragma unroll
    for (int kk = 0; kk < 2; ++kk) {
      bf16x8 af[4], bg[4];
      const int kb = kk * 32 + l4 * 8;
#pragma unroll
      for (int mt = 0; mt < 4; ++mt)
        af[mt] = *(const bf16x8*)(As + (wr + mt * 16 + l15) * 64 + kb);
#pragma unroll
      for (int nt = 0; nt < 4; ++nt)
        bg[nt] = *(const bf16x8*)(Bs + (wc + nt * 16 + l15) * 64 + kb);
#pragma unroll
      for (int mt = 0; mt < 4; ++mt)
#pragma unroll
        for (int nt = 0; nt < 4; ++nt)
          acc[mt][nt] = mfma16(af[mt], bg[nt], acc[mt][nt]);
    }
    __syncthreads();  // protect LDS before next stage
  }

  // epilogue. C/D: col = lane&15, row = (lane>>4)*4 + i
#pragma unroll
  for (int nt = 0; nt < 4; ++nt) {
    int gc = bcol + wc + nt * 16 + l15;
    float bv = bias[gc];
#pragma unroll
    for (int mt = 0; mt < 4; ++mt) {
#pragma unroll
      for (int i = 0; i < 4; ++i) {
        int gm = brow + wr + mt * 16 + l4 * 4 + i;
        float v = acc[mt][nt][i] + bv;
        if (MODE == 0) {
          ((u16*)outp)[(size_t)gm * 1024 + gc] = bf(v * (0.125f * LOG2E));
        } else if (MODE == 1) {
          ((u16*)outp)[(size_t)gm * 1024 + gc] = bf(v);
        } else if (MODE == 2) {
          ((u16*)outp)[((size_t)(gm >> 10) * 1024 + gc) * 1024 + (gm & 1023)] = bf(v);
        } else {
          ((float*)outp)[(size_t)gm * 1024 + gc] = v + resid[(size_t)gm * 1024 + gc];
        }
      }
    }
  }
}

// ---------------- attention: per (b,h), 16 q-rows per block ----------------
// q [m][d] bf16 (pre-scaled log2e/8), k [m][d] bf16, vt [b][d][seq] bf16
// scores kept bf16 in 32KB LDS (log2 domain) -> 5 blocks/CU
__global__ __launch_bounds__(256) void k_attn(const u16* __restrict__ q,
                                              const u16* __restrict__ kk_,
                                              const u16* __restrict__ vt,
                                              const float* __restrict__ pb,
                                              float* __restrict__ attn_out,
                                              u16* __restrict__ aout) {
  __shared__ __align__(16) u16 sp[16 * 1024];  // 32 KB bf16 scores/P
  const int tid = threadIdx.x;
  const int lane = tid & 63;
  const int wave = tid >> 6;
  // XCD-chunked swizzle: 8192 blocks, 1024 per XCD chunk -> same-bh contiguous
  const int bid = blockIdx.x;
  const int swz = (bid & 7) * 1024 + (bid >> 3);
  const int bh = swz >> 6;       // 0..127
  const int q0 = (swz & 63) * 16;
  const int b = bh >> 4, h = bh & 15;
  const int l15 = lane & 15, l4 = lane >> 4;

  // ---- phase 1: scores = (QK^T)*log2e/8 + pb*log2e -> bf16 LDS (swizzled) ----
  bf16x8 aq0, aq1;
  {
    const u16* qp = q + ((size_t)(b * 1024 + q0 + l15)) * 1024 + h * 64 + l4 * 8;
    aq0 = *(const bf16x8*)qp;
    aq1 = *(const bf16x8*)(qp + 32);
  }
  const int colbase = wave * 256;
#pragma unroll 4
  for (int nt = 0; nt < 16; ++nt) {
    int col = colbase + nt * 16 + l15;
    const u16* kp = kk_ + ((size_t)(b * 1024 + col)) * 1024 + h * 64 + l4 * 8;
    bf16x8 b0 = *(const bf16x8*)kp;
    bf16x8 b1 = *(const bf16x8*)(kp + 32);
    f32x4 c = {};
    c = mfma16(aq0, b0, c);
    c = mfma16(aq1, b1, c);
#pragma unroll
    for (int i = 0; i < 4; ++i) {
      int r = l4 * 4 + i;
      float v = fmaf(pb[(size_t)(q0 + r) * 1024 + col], LOG2E, c[i]);
      sp[r * 1024 + (col ^ ((r & 7) << 3))] = bf(v);
    }
  }
  __syncthreads();

  // ---- phase 2: softmax (exp2), 16 threads per row ----
  {
    const int r = tid >> 4;
    const int l = tid & 15;
    const int rx = (r & 7) << 3;
    u16* row = sp + r * 1024;
    float mx = -3e38f;
#pragma unroll
    for (int g = 0; g < 8; ++g) {
      bf16x8 v = *(const bf16x8*)(row + ((g * 128 + l * 8) ^ rx));
#pragma unroll
      for (int j = 0; j < 8; ++j) mx = fmaxf(mx, b2f(v[j]));
    }
#pragma unroll
    for (int o = 1; o < 16; o <<= 1) mx = fmaxf(mx, __shfl_xor(mx, o));
    float sum = 0.f;
#pragma unroll
    for (int g = 0; g < 8; ++g) {
      u16* p = row + ((g * 128 + l * 8) ^ rx);
      bf16x8 v = *(bf16x8*)p;
      bf16x8 e;
#pragma unroll
      for (int j = 0; j < 8; ++j) {
        float t = exp2f(b2f(v[j]) - mx);
        sum += t;
        e[j] = (short)bf(t);
      }
      *(bf16x8*)p = e;
    }
#pragma unroll
    for (int o = 1; o < 16; o <<= 1) sum += __shfl_xor(sum, o);
    float inv = 1.f / sum;
    float* gout = attn_out + ((size_t)bh * 1024 + q0 + r) * 1024;
#pragma unroll
    for (int g = 0; g < 8; ++g) {
      int c0 = g * 128 + l * 8;
      u16* p = row + (c0 ^ rx);
      bf16x8 v = *(bf16x8*)p;
      float4 w0, w1;
      bf16x8 e;
      w0.x = b2f(v[0]) * inv; w0.y = b2f(v[1]) * inv;
      w0.z = b2f(v[2]) * inv; w0.w = b2f(v[3]) * inv;
      w1.x = b2f(v[4]) * inv; w1.y = b2f(v[5]) * inv;
      w1.z = b2f(v[6]) * inv; w1.w = b2f(v[7]) * inv;
      e[0] = (short)bf(w0.x); e[1] = (short)bf(w0.y);
      e[2] = (short)bf(w0.z); e[3] = (short)bf(w0.w);
      e[4] = (short)bf(w1.x); e[5] = (short)bf(w1.y);
      e[6] = (short)bf(w1.z); e[7] = (short)bf(w1.w);
      *(bf16x8*)p = e;                    // normalized P for PV
      *(float4*)(gout + c0) = w0;         // attn output f32, coalesced
      *(float4*)(gout + c0 + 4) = w1;
    }
  }
  __syncthreads();

  // ---- phase 3: PV, each wave kv range [wave*256, +256) ----
  f32x4 pacc[4] = {};
  const int kvw = wave * 256;
#pragma unroll 2
  for (int ks = 0; ks < 8; ++ks) {
    const int c0 = kvw + ks * 32 + l4 * 8;
    bf16x8 af = *(const bf16x8*)(sp + l15 * 1024 + (c0 ^ ((l15 & 7) << 3)));
#pragma unroll
    for (int nt = 0; nt < 4; ++nt) {
      const u16* vp = vt + ((size_t)b * 1024 + h * 64 + nt * 16 + l15) * 1024 + c0;
      bf16x8 bv = *(const bf16x8*)vp;
      pacc[nt] = mfma16(af, bv, pacc[nt]);
    }
  }
  __syncthreads();

  // ---- phase 4: k-split reduce via LDS (reuse sp as f32) ----
  float* red = (float*)(void*)sp;  // 16 KB used
#pragma unroll
  for (int nt = 0; nt < 4; ++nt)
#pragma unroll
    for (int i = 0; i < 4; ++i)
      red[wave * 1024 + (l4 * 4 + i) * 64 + nt * 16 + l15] = pacc[nt][i];
  __syncthreads();
#pragma unroll
  for (int it = 0; it < 4; ++it) {
    int o = it * 256 + tid;
    int r = o >> 6, c = o & 63;
    float s = red[o] + red[1024 + o] + red[2048 + o] + red[3072 + o];
    aout[(size_t)(b * 1024 + q0 + r) * 1024 + h * 64 + c] = bf(s);
  }
}

// ---------------- LayerNorm: one wave per row ----------------
__global__ __launch_bounds__(256) void k_ln(const float* __restrict__ y,
                                            const float* __restrict__ g,
                                            const float* __restrict__ be,
                                            float* __restrict__ o) {
  const int lane = threadIdx.x & 63;
  const int wave = threadIdx.x >> 6;
  size_t row = (size_t)blockIdx.x * 4 + wave;
  const float* yr = y + row * 1024;
  float4 v[4];
  float s = 0.f, sq = 0.f;
#pragma unroll
  for (int i = 0; i < 4; ++i) {
    v[i] = *(const float4*)(yr + i * 256 + lane * 4);
    s += v[i].x + v[i].y + v[i].z + v[i].w;
    sq += v[i].x * v[i].x + v[i].y * v[i].y + v[i].z * v[i].z + v[i].w * v[i].w;
  }
#pragma unroll
  for (int off = 1; off < 64; off <<= 1) {
    s += __shfl_xor(s, off);
    sq += __shfl_xor(sq, off);
  }
  float mu = s * (1.f / 1024.f);
  float var = sq * (1.f / 1024.f) - mu * mu;
  float rs = rsqrtf(fmaxf(var, 0.f) + 1e-5f);
  float* orow = o + row * 1024;
#pragma unroll
  for (int i = 0; i < 4; ++i) {
    int c = i * 256 + lane * 4;
    float4 gg = *(const float4*)(g + c);
    float4 bb = *(const float4*)(be + c);
    float4 r;
    r.x = (v[i].x - mu) * rs * gg.x + bb.x;
    r.y = (v[i].y - mu) * rs * gg.y + bb.y;
    r.z = (v[i].z - mu) * rs * gg.z + bb.z;
    r.w = (v[i].w - mu) * rs * gg.w + bb.w;
    *(float4*)(orow + c) = r;
  }
}

extern "C" void kernel_launch(void* const* d_in, const int* in_sizes, int n_in,
                              void* d_out, int out_size, void* d_ws, size_t ws_size,
                              hipStream_t stream) {
  const float* x = (const float*)d_in[0];
  const float* Wq = (const float*)d_in[1];
  const float* bq = (const float*)d_in[2];
  const float* Wk = (const float*)d_in[3];
  const float* bk = (const float*)d_in[4];
  const float* Wv = (const float*)d_in[5];
  const float* bv = (const float*)d_in[6];
  const float* pb = (const float*)d_in[7];
  const float* Wo = (const float*)d_in[8];
  const float* bo = (const float*)d_in[9];
  const float* gamma = (const float*)d_in[10];
  const float* beta = (const float*)d_in[11];

  char* ws = (char*)d_ws;
  u16* xb = (u16*)(ws);            // 16MB, reused as aows after V gemm
  u16* aows = (u16*)(ws);
  u16* wqT = (u16*)(ws + (16u << 20));
  u16* wkT = (u16*)(ws + (18u << 20));
  u16* wvT = (u16*)(ws + (20u << 20));
  u16* woT = (u16*)(ws + (22u << 20));
  u16* qws = (u16*)(ws + (24u << 20));
  u16* kws = (u16*)(ws + (40u << 20));
  u16* vtws = (u16*)(ws + (56u << 20));
  float* yws = (float*)(ws + (72u << 20));

  float* out_ln = (float*)d_out;
  float* out_attn = out_ln + (size_t)Mm * Dd;

  k_cvt<<<8192, 256, 0, stream>>>(x, xb);
  k_tr<<<dim3(32, 32), dim3(32, 8), 0, stream>>>(Wq, wqT);
  k_tr<<<dim3(32, 32), dim3(32, 8), 0, stream>>>(Wk, wkT);
  k_tr<<<dim3(32, 32), dim3(32, 8), 0, stream>>>(Wv, wvT);
  k_tr<<<dim3(32, 32), dim3(32, 8), 0, stream>>>(Wo, woT);
  k_gemm<0><<<dim3(8, 64), 256, 0, stream>>>(xb, wqT, bq, nullptr, qws);
  k_gemm<1><<<dim3(8, 64), 256, 0, stream>>>(xb, wkT, bk, nullptr, kws);
  k_gemm<2><<<dim3(8, 64), 256, 0, stream>>>(xb, wvT, bv, nullptr, vtws);
  k_attn<<<8192, 256, 0, stream>>>(qws, kws, vtws, pb, out_attn, aows);
  k_gemm<3><<<dim3(8, 64), 256, 0, stream>>>(aows, woT, bo, x, yws);
  k_ln<<<2048, 256, 0, stream>>>(yws, gamma, beta, out_ln);
}